// Round 2
// baseline (139.252 us; speedup 1.0000x reference)
//
#include <hip/hip_runtime.h>
#include <math.h>

namespace {

constexpr int kS = 26;
constexpr int kA = 5;
constexpr int kP = kS * kS * kA;   // 3380
constexpr int kM = 30;
constexpr int kB = 128;
constexpr float kCW = 16.0f;       // IM / S
constexpr int kTA = 256;
constexpr int kChunks = (kP + kTA - 1) / kTA;  // 14

// ws layout (bytes):
//   [0, kB*kM*8)            u64 argmax keys, zero-initialized (0 => "no positive iou" => idx 0)
//   [kB*kM*8, +12)          float accum[3] = {obj_term, noobj_c2, loc}, zero-initialized
constexpr size_t kKeyBytes = (size_t)kB * kM * 8;  // 30720
constexpr size_t kZeroBytes = kKeyBytes + 3 * sizeof(float);

__device__ __forceinline__ float sig(float x) { return 1.0f / (1.0f + expf(-x)); }

// Monotone float->u32 map; +0 and -0 collapse to the same key (0x80000000),
// matching float == semantics for the argmax tie-break. Low 32 bits carry ~p
// so that equal iou prefers SMALLER p (first occurrence, like jnp.argmax).
__device__ __forceinline__ unsigned long long pack_key(float f, int p) {
  unsigned int u = __float_as_uint(f);
  unsigned int k = (f >= 0.0f) ? (u | 0x80000000u) : ~u;
  return ((unsigned long long)k << 32) |
         (unsigned long long)(0xFFFFFFFFu - (unsigned)p);
}

__global__ __launch_bounds__(kTA) void loss_A(
    const float* __restrict__ pred, const float* __restrict__ targ,
    const float* __restrict__ anch, unsigned long long* __restrict__ keys,
    float* __restrict__ accum) {
  __shared__ float s_gx1[kM], s_gx2[kM], s_gy1[kM], s_gy2[kM], s_ga[kM];
  __shared__ int s_valid[kM];
  __shared__ float s_anc[2 * kA];
  __shared__ float s_red[kTA / 64][2];

  const int b = blockIdx.y;
  const int tid = threadIdx.x;
  const int p = blockIdx.x * kTA + tid;
  const int lane = tid & 63;
  const int wid = tid >> 6;

  if (tid < 2 * kA) s_anc[tid] = anch[tid];
  if (tid < kM) {
    const float t0 = targ[b * kM * 5 + tid * 5 + 0];
    const float t1 = targ[b * kM * 5 + tid * 5 + 1];
    const float t2 = targ[b * kM * 5 + tid * 5 + 2];
    const float t3 = targ[b * kM * 5 + tid * 5 + 3];
    const float t4 = targ[b * kM * 5 + tid * 5 + 4];
    const float gxc = t0 + t2 * 0.5f;
    const float gyc = t1 + t3 * 0.5f;
    const float gw = t2 - t0;  // faithful to source
    const float gh = t3 * t1;  // faithful to source
    s_gx1[tid] = gxc - gw * 0.5f;
    s_gx2[tid] = gxc + gw * 0.5f;
    s_gy1[tid] = gyc - gh * 0.5f;
    s_gy2[tid] = gyc + gh * 0.5f;
    s_ga[tid] = gw * gh;
    s_valid[tid] = (t4 == 1.0f) ? 1 : 0;
  }
  __syncthreads();

  const bool active = (p < kP);
  float4 box = make_float4(0.f, 0.f, 0.f, 0.f);
  float c = 0.0f;
  if (active) {
    const float* pp = pred + ((size_t)b * kP + p) * 25;
    const float s0 = sig(pp[0]);
    const float s1 = sig(pp[1]);
    const float s2 = sig(pp[2]) * 0.5f;
    const float s3 = sig(pp[3]) * 0.5f;
    c = sig(pp[4]);
    const int a = p % kA;
    const int gx = (p / kA) % kS;
    const int gy = p / (kA * kS);
    box.x = (s0 + (float)gx) * kCW;
    box.y = (s1 + (float)gy) * kCW;
    box.z = expf(s2) * s_anc[2 * a + 0] * kCW;
    box.w = expf(s3) * s_anc[2 * a + 1] * kCW;
  }
  const float hw = box.z * 0.5f, hh = box.w * 0.5f;
  const float px1 = box.x - hw, px2 = box.x + hw;  // exactly pbox[...,0] -+ pbox[...,2]/2
  const float py1 = box.y - hh, py2 = box.y + hh;
  const float ap = box.z * box.w;

  bool obj = false;
  for (int m = 0; m < kM; ++m) {
    if (!s_valid[m]) continue;  // wave-uniform (same b across block)
    float dx = fminf(s_gx2[m], px2) - fmaxf(s_gx1[m], px1);
    float dy = fminf(s_gy2[m], py2) - fmaxf(s_gy1[m], py1);
    dx = fmaxf(dx, 0.0f);
    dy = fmaxf(dy, 0.0f);
    const float inter = dx * dy;
    const float iou = inter / (s_ga[m] + ap - inter + 1e-9f);
    const bool pos = active && (iou > 0.0f);
    obj = obj || (iou > 0.6f && active);
    // Lanes with iou <= 0 can never be the argmax when any positive exists;
    // when NO positive exists anywhere, key stays 0 => decoded as idx 0,
    // which equals jnp.argmax of an all-(+-0) row.
    if (__any(pos)) {
      unsigned long long k = pos ? pack_key(iou, p) : 0ull;
#pragma unroll
      for (int off = 32; off > 0; off >>= 1) {
        const unsigned long long o = __shfl_down(k, off);
        if (o > k) k = o;
      }
      if (lane == 0) atomicMax(&keys[b * kM + m], k);
    }
  }

  // conf terms: obj -> (c-1)^2, else noobj c^2
  float objt = 0.0f, noob = 0.0f;
  if (active) {
    if (obj) {
      const float d = c - 1.0f;
      objt = d * d;
    } else {
      noob = c * c;
    }
  }
#pragma unroll
  for (int off = 32; off > 0; off >>= 1) {
    objt += __shfl_down(objt, off);
    noob += __shfl_down(noob, off);
  }
  if (lane == 0) {
    s_red[wid][0] = objt;
    s_red[wid][1] = noob;
  }
  __syncthreads();
  if (tid == 0) {
    float a0 = 0.f, a1 = 0.f;
    for (int w = 0; w < kTA / 64; ++w) {
      a0 += s_red[w][0];
      a1 += s_red[w][1];
    }
    atomicAdd(&accum[0], a0);
    atomicAdd(&accum[1], a1);
  }
}

__global__ __launch_bounds__(64) void loss_B(
    const float* __restrict__ pred, const float* __restrict__ targ,
    const float* __restrict__ anch, const unsigned long long* __restrict__ keys,
    float* __restrict__ accum) {
  const int b = blockIdx.x;
  const int m = threadIdx.x;  // one wave; lanes 0..29 carry GTs
  int idx = -1;
  int valid = 0;
  float t0 = 0.f, t1 = 0.f, t2 = 0.f, t3 = 0.f;
  if (m < kM) {
    const unsigned long long k = keys[b * kM + m];
    idx = (k == 0ull) ? 0 : (int)(0xFFFFFFFFu - (unsigned)(k & 0xFFFFFFFFull));
    t0 = targ[b * kM * 5 + m * 5 + 0];
    t1 = targ[b * kM * 5 + m * 5 + 1];
    t2 = targ[b * kM * 5 + m * 5 + 2];
    t3 = targ[b * kM * 5 + m * 5 + 3];
    valid = (targ[b * kM * 5 + m * 5 + 4] == 1.0f) ? 1 : 0;
  }
  // last-valid-m-wins dedup (matches R1-passing semantics)
  bool dead = false;
  for (int j = 1; j < kM; ++j) {
    const int idx2 = __shfl(idx, j);
    const int v2 = __shfl(valid, j);
    if (j > m && v2 && idx2 == idx) dead = true;
  }
  float loc = 0.0f;
  if (m < kM && valid && !dead) {
    const float gxc = t0 + t2 * 0.5f;
    const float gyc = t1 + t3 * 0.5f;
    const int ra = idx % kA;
    const int rw = (idx / kA) % kS;
    const int rh = idx / (kA * kS);
    const float tx = (gxc - (float)rw * kCW) / kCW;
    const float ty = (gyc - (float)rh * kCW) / kCW;
    const float tw = logf((t2 / kCW) / anch[2 * ra + 0]);
    const float th = logf((t3 / kCW) / anch[2 * ra + 1]);
    const float* pp = pred + ((size_t)b * kP + idx) * 25;
    const float d0 = sig(pp[0]) - tx;
    const float d1 = sig(pp[1]) - ty;
    const float d2 = sig(pp[2]) * 0.5f - tw;
    const float d3 = sig(pp[3]) * 0.5f - th;
    loc = d0 * d0 + d1 * d1 + d2 * d2 + d3 * d3;
  }
#pragma unroll
  for (int off = 32; off > 0; off >>= 1) loc += __shfl_down(loc, off);
  if (m == 0) atomicAdd(&accum[2], loc);
}

__global__ void loss_C(const float* __restrict__ accum, float* __restrict__ out) {
  if (threadIdx.x == 0) {
    const float loss_conf = (accum[0] + 0.5f * accum[1]) / (float)kB;
    const float loss_loc = 5.0f * accum[2] / (float)kB;
    out[0] = loss_loc + loss_conf;
    out[1] = loss_loc;
    out[2] = loss_conf;
  }
}

}  // namespace

extern "C" void kernel_launch(void* const* d_in, const int* in_sizes, int n_in,
                              void* d_out, int out_size, void* d_ws, size_t ws_size,
                              hipStream_t stream) {
  const float* pred = (const float*)d_in[0];
  const float* targ = (const float*)d_in[1];
  const float* anch = (const float*)d_in[2];
  float* out = (float*)d_out;
  unsigned long long* keys = (unsigned long long*)d_ws;
  float* accum = (float*)((char*)d_ws + kKeyBytes);

  hipMemsetAsync(d_ws, 0, kZeroBytes, stream);
  loss_A<<<dim3(kChunks, kB), kTA, 0, stream>>>(pred, targ, anch, keys, accum);
  loss_B<<<kB, 64, 0, stream>>>(pred, targ, anch, keys, accum);
  loss_C<<<1, 64, 0, stream>>>(accum, out);
}